// Round 5
// baseline (588.989 us; speedup 1.0000x reference)
//
#include <hip/hip_runtime.h>

typedef unsigned int uint;
typedef unsigned short ushort_t;
typedef unsigned long long u64;
typedef __attribute__((ext_vector_type(4))) float f32x4;
typedef __attribute__((ext_vector_type(8))) __bf16 bf16x8;
typedef __attribute__((ext_vector_type(8))) unsigned short us8;

#define BATCH 65536
#define VEC 512
#define K 1024
#define GAMMA 0.99f
#define EPS 1e-05f
#define SEG 64

// 8-phase GEMM geometry
#define BM 256
#define BN 128
#define BK 32
#define NKT (VEC / BK)      // 16 K-tiles
#define ASLOT 2048          // us8 granules per A K-tile (256 rows x 32 k x hi/lo)
#define BSLOT 1024          // us8 granules per B K-tile (128 cols x 32 k x hi/lo)
#define SLOT (ASLOT + BSLOT)

__device__ __forceinline__ ushort_t hi_of(float f) {
    return (ushort_t)(__float_as_uint(f) >> 16);
}
__device__ __forceinline__ ushort_t lo_of(float f) {
    float fhi = __uint_as_float(__float_as_uint(f) & 0xffff0000u);
    return (ushort_t)(__float_as_uint(f - fhi) >> 16);
}

__device__ __forceinline__ void gl16(const void* g, void* l) {
    __builtin_amdgcn_global_load_lds(
        (const __attribute__((address_space(1))) unsigned int*)g,
        (__attribute__((address_space(3))) unsigned int*)l, 16, 0, 0);
}

// ---- column norms of weight (VEC,K) ----
__global__ void k_w2(const float* __restrict__ w, float* __restrict__ w2) {
    __shared__ float red[16][17];
    const int c = blockIdx.x * 16 + (threadIdx.x & 15);
    const int vg = threadIdx.x >> 4;
    float s = 0.f;
    for (int i = 0; i < 32; ++i) {
        float t = w[(size_t)(vg * 32 + i) * K + c];
        s += t * t;
    }
    red[vg][threadIdx.x & 15] = s;
    __syncthreads();
    if (vg == 0) {
        float acc = 0.f;
#pragma unroll
        for (int g = 0; g < 16; ++g) acc += red[g][threadIdx.x & 15];
        w2[c] = acc;
    }
}

// ---- pack w into B granules: [gx 8][ks 16][ct 8][half 2][lane 64] us8 ----
__global__ void k_pack_w(const float* __restrict__ w, us8* __restrict__ wpk) {
    const int g = blockIdx.x;            // gx*16 + ks
    const int gx = g >> 4, ks = g & 15;
    const int t = threadIdx.x;
    us8* dst = wpk + (size_t)g * 1024;
#pragma unroll
    for (int i = 0; i < 4; ++i) {
        const int o = i * 256 + t;
        const int lane = o & 63, half = (o >> 6) & 1, ct = o >> 7;
        const int col = gx * 128 + ct * 16 + (lane & 15);
        const int kb = ks * 32 + (lane >> 4) * 8;
        us8 v;
#pragma unroll
        for (int j = 0; j < 8; ++j) {
            float f = w[(size_t)(kb + j) * K + col];
            v[j] = half ? lo_of(f) : hi_of(f);
        }
        dst[o] = v;
    }
}

// ---- pack x into A granules: [gy 256][ks 16][slab 16][half 2][lane 64] us8 ----
__global__ void k_pack_x(const float* __restrict__ x, us8* __restrict__ xpk) {
    const int gy = blockIdx.x >> 3, q = blockIdx.x & 7;
    const int t = threadIdx.x;
    us8* dst = xpk + (size_t)gy * (NKT * ASLOT);
#pragma unroll
    for (int jj = 0; jj < 16; ++jj) {
        const int o = q * 4096 + jj * 256 + t;
        const int ks = o >> 11;
        const int rem = o & 2047;
        const int slab = rem >> 7, half = (rem >> 6) & 1, lane = rem & 63;
        const int row = gy * BM + slab * 16 + (lane & 15);
        const int kb = ks * 32 + (lane >> 4) * 8;
        const float4* p = (const float4*)(x + (size_t)row * VEC + kb);
        float4 f0 = p[0], f1 = p[1];
        float ff[8] = {f0.x, f0.y, f0.z, f0.w, f1.x, f1.y, f1.z, f1.w};
        us8 v;
#pragma unroll
        for (int j = 0; j < 8; ++j) v[j] = half ? lo_of(ff[j]) : hi_of(ff[j]);
        dst[o] = v;
    }
}

// ---- 8-phase split-bf16 MFMA distance GEMM + per-row argmin merge ----
// 2048 blocks x 512 thr; 8 waves (4M x 2N); per-wave 64x64; 3-slot LDS pipeline.
__launch_bounds__(512, 2)
__global__ void k_gemm8(const us8* __restrict__ xpk, const us8* __restrict__ wpk,
                        const float* __restrict__ w2, u64* __restrict__ keys) {
    __shared__ us8 lds[3 * SLOT];   // 144 KB

    const int blk = blockIdx.x;
    const int gy = (blk & 7) * 32 + (blk >> 6);     // XCD-chunked, bijective (2048%8==0)
    const int gx = (blk >> 3) & 7;
    const int t = threadIdx.x;
    const int lane = t & 63;
    const int wv = t >> 6;
    const int wm = wv >> 1, wn = wv & 1;

    const us8* asrc = xpk + (size_t)gy * (NKT * ASLOT);
    const us8* bsrc = wpk + (size_t)gx * (NKT * BSLOT);

    f32x4 acc[4][4];
#pragma unroll
    for (int i = 0; i < 4; ++i)
#pragma unroll
        for (int j = 0; j < 4; ++j) acc[i][j] = (f32x4){0.f, 0.f, 0.f, 0.f};

    // prologue: stage tiles 0,1 into slots 0,1 (6 wave-loads each)
#pragma unroll
    for (int tt = 0; tt < 2; ++tt) {
        us8* d = &lds[tt * SLOT];
        const us8* sa = asrc + tt * ASLOT;
        const us8* sb = bsrc + tt * BSLOT;
        gl16(sa + t, d + t);
        gl16(sa + 512 + t, d + 512 + t);
        gl16(sa + 1024 + t, d + 1024 + t);
        gl16(sa + 1536 + t, d + 1536 + t);
        gl16(sb + t, d + ASLOT + t);
        gl16(sb + 512 + t, d + ASLOT + 512 + t);
    }
    asm volatile("s_waitcnt vmcnt(6)" ::: "memory");   // tile0 landed; tile1 in flight
    __builtin_amdgcn_s_barrier();
    asm volatile("" ::: "memory");

    int slot = 0;
    for (int tk = 0; tk < NKT; ++tk) {
        const us8* A = &lds[slot * SLOT];
        const us8* B = A + ASLOT;
        const int s2 = (slot >= 1) ? slot - 1 : 2;     // (tk+2)%3: holds fully-consumed tk-1
        us8* d2 = &lds[s2 * SLOT];
        const bool st = (tk + 2 < NKT);
        const us8* sa2 = asrc + (tk + 2) * ASLOT;
        const us8* sb2 = bsrc + (tk + 2) * BSLOT;

#pragma unroll
        for (int q = 0; q < 4; ++q) {
            const int qm = q >> 1, qn = q & 1;
            bf16x8 ah[2], al[2], bh[2], bl[2];
#pragma unroll
            for (int i = 0; i < 2; ++i) {
                const int slab = wm * 4 + qm * 2 + i;
                ah[i] = __builtin_bit_cast(bf16x8, A[slab * 128 + lane]);
                al[i] = __builtin_bit_cast(bf16x8, A[slab * 128 + 64 + lane]);
                const int ct = wn * 4 + qn * 2 + i;
                bh[i] = __builtin_bit_cast(bf16x8, B[ct * 128 + lane]);
                bl[i] = __builtin_bit_cast(bf16x8, B[ct * 128 + 64 + lane]);
            }
            // stage tile tk+2 into s2: {2,2,1,1} wave-loads across the 4 phases
            if (st) {
                if (q == 0) { gl16(sa2 + t, d2 + t); gl16(sa2 + 512 + t, d2 + 512 + t); }
                else if (q == 1) { gl16(sa2 + 1024 + t, d2 + 1024 + t); gl16(sa2 + 1536 + t, d2 + 1536 + t); }
                else if (q == 2) { gl16(sb2 + t, d2 + ASLOT + t); }
                else { gl16(sb2 + 512 + t, d2 + ASLOT + 512 + t); }
            }
            asm volatile("" ::: "memory");
            __builtin_amdgcn_s_barrier();
            asm volatile("s_waitcnt lgkmcnt(0)" ::: "memory");
            __builtin_amdgcn_sched_barrier(0);
            __builtin_amdgcn_s_setprio(1);
#pragma unroll
            for (int i = 0; i < 2; ++i)
#pragma unroll
                for (int j = 0; j < 2; ++j) {
                    const int m = qm * 2 + i, n = qn * 2 + j;
                    acc[m][n] = __builtin_amdgcn_mfma_f32_16x16x32_bf16(ah[i], bh[j], acc[m][n], 0, 0, 0);
                    acc[m][n] = __builtin_amdgcn_mfma_f32_16x16x32_bf16(ah[i], bl[j], acc[m][n], 0, 0, 0);
                    acc[m][n] = __builtin_amdgcn_mfma_f32_16x16x32_bf16(al[i], bh[j], acc[m][n], 0, 0, 0);
                }
            __builtin_amdgcn_s_setprio(0);
            if (q == 3) {
                if (tk < NKT - 2)       asm volatile("s_waitcnt vmcnt(6)" ::: "memory");
                else if (tk == NKT - 2) asm volatile("s_waitcnt vmcnt(0)" ::: "memory");
            }
            asm volatile("" ::: "memory");
            __builtin_amdgcn_s_barrier();
            asm volatile("" ::: "memory");
        }
        slot = (slot < 2) ? slot + 1 : 0;
    }

    // epilogue: dist = w2 - 2*dot, per-row argmin, global atomicMin merge
    const int col_base = gx * BN + wn * 64;
    float w2c[4];
#pragma unroll
    for (int ct = 0; ct < 4; ++ct) w2c[ct] = w2[col_base + ct * 16 + (lane & 15)];

#pragma unroll
    for (int rt = 0; rt < 4; ++rt) {
#pragma unroll
        for (int reg = 0; reg < 4; ++reg) {
            u64 km = ~0ull;
#pragma unroll
            for (int ct = 0; ct < 4; ++ct) {
                float dist = w2c[ct] - 2.0f * acc[rt][ct][reg];
                uint su = __float_as_uint(dist);
                su = (su & 0x80000000u) ? ~su : (su | 0x80000000u);
                const int col = col_base + ct * 16 + (lane & 15);
                u64 key = ((u64)su << 32) | (uint)col;
                km = key < km ? key : km;
            }
#pragma unroll
            for (int m = 1; m < 16; m <<= 1) {
                u64 o = __shfl_xor((unsigned long long)km, m);
                km = o < km ? o : km;
            }
            if ((lane & 15) == 0) {
                const int row = gy * BM + wm * 64 + rt * 16 + (lane >> 4) * 4 + reg;
                atomicMin((unsigned long long*)&keys[row], (unsigned long long)km);
            }
        }
    }
}

// ---- fallback GEMM (reg-staged A, packed B), used only if ws too small ----
__launch_bounds__(256, 2)
__global__ void k_gemm_fb(const float* __restrict__ x, const us8* __restrict__ wpk,
                          const float* __restrict__ w2, u64* __restrict__ keys) {
    __shared__ us8 a_lds[2][1024];
    __shared__ us8 b_lds[2][1024];

    const int blk = blockIdx.x;
    const int gy = (blk & 7) * 64 + ((blk >> 3) >> 3);
    const int gx = (blk >> 3) & 7;
    const int row0 = gy * 128;
    const int col0 = gx * 128;
    const int t = threadIdx.x;
    const int wv = t >> 6, lane = t & 63;

    const int arow_base = (t >> 6) * 16 + (t & 15);
    const int akoff = ((t >> 4) & 3) * 8;
    float4 af[2][2];

    auto aload = [&](int ks) {
#pragma unroll
        for (int r = 0; r < 2; ++r) {
            const float4* p = (const float4*)(x + (size_t)(row0 + arow_base + r * 64) * VEC + ks * 32 + akoff);
            af[r][0] = p[0];
            af[r][1] = p[1];
        }
    };
    auto awrite = [&](int buf) {
#pragma unroll
        for (int r = 0; r < 2; ++r) {
            const float* ff = (const float*)&af[r][0];
            us8 h, l;
#pragma unroll
            for (int j = 0; j < 8; ++j) { h[j] = hi_of(ff[j]); l[j] = lo_of(ff[j]); }
            const int c0 = (r * 4 + (t >> 6)) * 128 + (t & 63);
            a_lds[buf][c0] = h;
            a_lds[buf][c0 + 64] = l;
        }
    };
    auto bstage = [&](int ks, int buf) {
        const us8* src = wpk + (size_t)(gx * 16 + ks) * 1024;
#pragma unroll
        for (int r = 0; r < 4; ++r)
            gl16(src + r * 256 + t, &b_lds[buf][r * 256 + t]);
    };

    const int wr = wv >> 1, wc = wv & 1;

    f32x4 acc[4][4];
#pragma unroll
    for (int i = 0; i < 4; ++i)
#pragma unroll
        for (int j = 0; j < 4; ++j) acc[i][j] = (f32x4){0.f, 0.f, 0.f, 0.f};

    aload(0);
    awrite(0);
    bstage(0, 0);
    __syncthreads();

    for (int ks = 0; ks < 16; ++ks) {
        const int buf = ks & 1;
        const bool next = (ks + 1 < 16);
        if (next) {
            aload(ks + 1);
            bstage(ks + 1, buf ^ 1);
        }
        bf16x8 ah[4], al[4];
#pragma unroll
        for (int rt = 0; rt < 4; ++rt) {
            const int c0 = (wr * 4 + rt) * 128 + lane;
            ah[rt] = __builtin_bit_cast(bf16x8, a_lds[buf][c0]);
            al[rt] = __builtin_bit_cast(bf16x8, a_lds[buf][c0 + 64]);
        }
#pragma unroll
        for (int ct = 0; ct < 4; ++ct) {
            const int c0 = (wc * 4 + ct) * 128 + lane;
            bf16x8 bh = __builtin_bit_cast(bf16x8, b_lds[buf][c0]);
            bf16x8 bl = __builtin_bit_cast(bf16x8, b_lds[buf][c0 + 64]);
#pragma unroll
            for (int rt = 0; rt < 4; ++rt) {
                acc[rt][ct] = __builtin_amdgcn_mfma_f32_16x16x32_bf16(ah[rt], bh, acc[rt][ct], 0, 0, 0);
                acc[rt][ct] = __builtin_amdgcn_mfma_f32_16x16x32_bf16(ah[rt], bl, acc[rt][ct], 0, 0, 0);
                acc[rt][ct] = __builtin_amdgcn_mfma_f32_16x16x32_bf16(al[rt], bh, acc[rt][ct], 0, 0, 0);
            }
        }
        if (next) awrite(buf ^ 1);
        __syncthreads();
    }

    float w2c[4];
#pragma unroll
    for (int ct = 0; ct < 4; ++ct)
        w2c[ct] = w2[col0 + wc * 64 + ct * 16 + (lane & 15)];

#pragma unroll
    for (int rt = 0; rt < 4; ++rt) {
#pragma unroll
        for (int reg = 0; reg < 4; ++reg) {
            u64 km = ~0ull;
#pragma unroll
            for (int ct = 0; ct < 4; ++ct) {
                float dist = w2c[ct] - 2.0f * acc[rt][ct][reg];
                uint su = __float_as_uint(dist);
                su = (su & 0x80000000u) ? ~su : (su | 0x80000000u);
                const int col = col0 + wc * 64 + ct * 16 + (lane & 15);
                u64 key = ((u64)su << 32) | (uint)col;
                km = key < km ? key : km;
            }
#pragma unroll
            for (int m = 1; m < 16; m <<= 1) {
                u64 o = __shfl_xor((unsigned long long)km, m);
                km = o < km ? o : km;
            }
            if ((lane & 15) == 0) {
                const int row = row0 + wr * 64 + rt * 16 + (lane >> 4) * 4 + reg;
                atomicMin((unsigned long long*)&keys[row], (unsigned long long)km);
            }
        }
    }
}

// ---- histogram from keys ----
__global__ void k_hist(const u64* __restrict__ keys, int* __restrict__ counts) {
    const int b = blockIdx.x * blockDim.x + threadIdx.x;
    atomicAdd(&counts[(uint)(keys[b] & 0xffffffffull)], 1);
}

// ---- scan of counts -> offsets; EMA cluster sizes -> cs ----
__global__ void k_scan(const int* __restrict__ counts,
                       const float* __restrict__ cluster_size,
                       int* __restrict__ offsets, float* __restrict__ cs) {
    __shared__ int sa[K];
    __shared__ int sb[K];
    __shared__ float sf[K];
    const int t = threadIdx.x;
    const int c = counts[t];

    sa[t] = c;
    __syncthreads();
    int* src = sa;
    int* dst = sb;
    for (int d = 1; d < K; d <<= 1) {
        dst[t] = src[t] + ((t >= d) ? src[t - d] : 0);
        __syncthreads();
        int* tmp = src; src = dst; dst = tmp;
    }
    offsets[t] = src[t] - c;

    float ncs = GAMMA * cluster_size[t] + (1.0f - GAMMA) * ((c == 0) ? 1.0f : (float)c);
    sf[t] = ncs;
    __syncthreads();
    for (int d = K / 2; d > 0; d >>= 1) {
        if (t < d) sf[t] += sf[t + d];
        __syncthreads();
    }
    float n = sf[0];
    cs[t] = (ncs + EPS) / (n + (float)K * EPS) * n;
}

// ---- counting-sort scatter ----
__global__ void k_scatter(const u64* __restrict__ keys, const int* __restrict__ offsets,
                          int* __restrict__ cursor, int* __restrict__ sorted,
                          int* __restrict__ sortedk) {
    const int b = blockIdx.x * blockDim.x + threadIdx.x;
    const int k = (int)(uint)(keys[b] & 0xffffffffull);
    const int pos = atomicAdd(&cursor[k], 1);
    sorted[offsets[k] + pos] = b;
    sortedk[offsets[k] + pos] = k;
}

// ---- balanced segmented reduction: 64 sorted rows per block ----
__launch_bounds__(512)
__global__ void k_segred(const float* __restrict__ x, const int* __restrict__ sorted,
                         const int* __restrict__ sortedk, float* __restrict__ esum) {
    __shared__ int srow[SEG];
    __shared__ int skid[SEG];
    const int b = blockIdx.x;
    const int t = threadIdx.x;
    if (t < SEG) {
        srow[t] = sorted[b * SEG + t];
        skid[t] = sortedk[b * SEG + t];
    }
    __syncthreads();

    float a = 0.f;
    int cur = skid[0];
#pragma unroll 8
    for (int i = 0; i < SEG; ++i) {
        const int k = skid[i];
        if (k != cur) {
            atomicAdd(&esum[(size_t)cur * VEC + t], a);
            a = 0.f;
            cur = k;
        }
        a += x[(size_t)srow[i] * VEC + t];
    }
    atomicAdd(&esum[(size_t)cur * VEC + t], a);
}

// ---- finalize: transpose esum (K,VEC)->(VEC,K), EMA + normalize ----
__launch_bounds__(256)
__global__ void k_finalize(const float* __restrict__ esum, const float* __restrict__ embed_avg,
                           const float* __restrict__ cs, float* __restrict__ out) {
    __shared__ float tile[64][65];
    const int k0 = blockIdx.x * 64;
    const int v0 = blockIdx.y * 64;
    const int c = threadIdx.x & 63;
    const int r0 = threadIdx.x >> 6;
#pragma unroll
    for (int j = 0; j < 16; ++j) {
        const int r = r0 + j * 4;
        tile[r][c] = esum[(size_t)(k0 + r) * VEC + v0 + c];
    }
    __syncthreads();
    const float csk = cs[k0 + c];
#pragma unroll
    for (int j = 0; j < 16; ++j) {
        const int r = r0 + j * 4;
        const size_t o = (size_t)(v0 + r) * K + k0 + c;
        out[o] = (GAMMA * embed_avg[o] + (1.0f - GAMMA) * tile[c][r]) / csk;
    }
}

extern "C" void kernel_launch(void* const* d_in, const int* in_sizes, int n_in,
                              void* d_out, int out_size, void* d_ws, size_t ws_size,
                              hipStream_t stream) {
    const float* x            = (const float*)d_in[0];   // (BATCH, VEC)
    const float* w            = (const float*)d_in[1];   // (VEC, K)
    const float* cluster_size = (const float*)d_in[2];   // (K,)
    const float* embed_avg    = (const float*)d_in[3];   // (VEC, K)
    float* out = (float*)d_out;                          // (VEC, K)

    // ws: keys | w2 | cs | counts | cursor | offsets | sorted | sortedk | esum | wpk | xpk
    u64*   keys    = (u64*)d_ws;
    float* w2      = (float*)(keys + BATCH);
    float* cs      = w2 + K;
    int*   counts  = (int*)(cs + K);
    int*   cursor  = counts + K;
    int*   offsets = cursor + K;
    int*   sorted  = offsets + K;
    int*   sortedk = sorted + BATCH;
    float* esum    = (float*)(sortedk + BATCH);          // (K, VEC), 2 MB
    us8*   wpk     = (us8*)(esum + (size_t)K * VEC);     // 2 MB
    us8*   xpk     = wpk + (size_t)128 * 1024;           // 128 MB
    const size_t need_apk = (size_t)((char*)(xpk + (size_t)256 * 32768) - (char*)d_ws);
    const bool apk = (ws_size >= need_apk);

    hipMemsetAsync(keys, 0xFF, (size_t)BATCH * sizeof(u64), stream);
    hipMemsetAsync(counts, 0, 2 * K * sizeof(int), stream);          // counts + cursor
    hipMemsetAsync(esum, 0, (size_t)K * VEC * sizeof(float), stream);

    k_w2<<<K / 16, 256, 0, stream>>>(w, w2);
    k_pack_w<<<128, 256, 0, stream>>>(w, wpk);
    if (apk) {
        k_pack_x<<<2048, 256, 0, stream>>>(x, xpk);
        k_gemm8<<<2048, 512, 0, stream>>>(xpk, wpk, w2, keys);
    } else {
        k_gemm_fb<<<4096, 256, 0, stream>>>(x, wpk, w2, keys);
    }
    k_hist<<<BATCH / 256, 256, 0, stream>>>(keys, counts);
    k_scan<<<1, K, 0, stream>>>(counts, cluster_size, offsets, cs);
    k_scatter<<<BATCH / 256, 256, 0, stream>>>(keys, offsets, cursor, sorted, sortedk);
    k_segred<<<BATCH / SEG, 512, 0, stream>>>(x, sorted, sortedk, esum);
    k_finalize<<<dim3(K / 64, VEC / 64), 256, 0, stream>>>(esum, embed_avg, cs, out);
}

// Round 6
// 497.823 us; speedup vs baseline: 1.1831x; 1.1831x over previous
//
#include <hip/hip_runtime.h>

typedef unsigned int uint;
typedef unsigned short ushort_t;
typedef unsigned long long u64;
typedef __attribute__((ext_vector_type(4))) float f32x4;
typedef __attribute__((ext_vector_type(8))) __bf16 bf16x8;
typedef __attribute__((ext_vector_type(8))) unsigned short us8;

#define BATCH 65536
#define VEC 512
#define K 1024
#define GAMMA 0.99f
#define EPS 1e-05f
#define SEG 64

// GEMM geometry: 256x256 tile, 8 waves (2M x 4N), per-wave 128x64, BK=32
#define BM 256
#define BN 256
#define NKT (VEC / 32)      // 16 K-tiles
#define ASLOT 2048          // us8 granules per A K-tile (256 rows x 32k x hi/lo)
#define BSLOT 2048          // us8 granules per B K-tile (256 cols x 32k x hi/lo)

__device__ __forceinline__ ushort_t hi_of(float f) {
    return (ushort_t)(__float_as_uint(f) >> 16);
}
__device__ __forceinline__ ushort_t lo_of(float f) {
    float fhi = __uint_as_float(__float_as_uint(f) & 0xffff0000u);
    return (ushort_t)(__float_as_uint(f - fhi) >> 16);
}

__device__ __forceinline__ void gl16(const void* g, void* l) {
    __builtin_amdgcn_global_load_lds(
        (const __attribute__((address_space(1))) unsigned int*)g,
        (__attribute__((address_space(3))) unsigned int*)l, 16, 0, 0);
}

// ---- column norms of weight (VEC,K) ----
__global__ void k_w2(const float* __restrict__ w, float* __restrict__ w2) {
    __shared__ float red[16][17];
    const int c = blockIdx.x * 16 + (threadIdx.x & 15);
    const int vg = threadIdx.x >> 4;
    float s = 0.f;
    for (int i = 0; i < 32; ++i) {
        float t = w[(size_t)(vg * 32 + i) * K + c];
        s += t * t;
    }
    red[vg][threadIdx.x & 15] = s;
    __syncthreads();
    if (vg == 0) {
        float acc = 0.f;
#pragma unroll
        for (int g = 0; g < 16; ++g) acc += red[g][threadIdx.x & 15];
        w2[c] = acc;
    }
}

// ---- pack w into B granules: [gx 4][ks 16][ct 16][half 2][lane 64] us8 ----
__global__ void k_pack_w(const float* __restrict__ w, us8* __restrict__ wpk) {
    const int g = blockIdx.x;            // gx*16 + ks, 64 blocks
    const int gx = g >> 4, ks = g & 15;
    const int t = threadIdx.x;
    us8* dst = wpk + (size_t)g * BSLOT;
#pragma unroll
    for (int i = 0; i < 8; ++i) {
        const int o = i * 256 + t;       // 0..2047
        const int lane = o & 63, half = (o >> 6) & 1, ct = o >> 7;
        const int col = gx * BN + ct * 16 + (lane & 15);
        const int kb = ks * 32 + (lane >> 4) * 8;
        us8 v;
#pragma unroll
        for (int j = 0; j < 8; ++j) {
            float f = w[(size_t)(kb + j) * K + col];
            v[j] = half ? lo_of(f) : hi_of(f);
        }
        dst[o] = v;
    }
}

// ---- pack x into A granules: [gy 256][ks 16][slab 16][half 2][lane 64] us8 ----
__global__ void k_pack_x(const float* __restrict__ x, us8* __restrict__ xpk) {
    const int gy = blockIdx.x >> 3, q = blockIdx.x & 7;
    const int t = threadIdx.x;
    us8* dst = xpk + (size_t)gy * (NKT * ASLOT);
#pragma unroll
    for (int jj = 0; jj < 16; ++jj) {
        const int o = q * 4096 + jj * 256 + t;
        const int ks = o >> 11;
        const int rem = o & 2047;
        const int slab = rem >> 7, half = (rem >> 6) & 1, lane = rem & 63;
        const int row = gy * BM + slab * 16 + (lane & 15);
        const int kb = ks * 32 + (lane >> 4) * 8;
        const float4* p = (const float4*)(x + (size_t)row * VEC + kb);
        float4 f0 = p[0], f1 = p[1];
        float ff[8] = {f0.x, f0.y, f0.z, f0.w, f1.x, f1.y, f1.z, f1.w};
        us8 v;
#pragma unroll
        for (int j = 0; j < 8; ++j) v[j] = half ? lo_of(ff[j]) : hi_of(ff[j]);
        dst[o] = v;
    }
}

// ---- main: 256x256 split-bf16 MFMA distance GEMM + per-row argmin merge ----
// 1024 blocks x 512 thr (8 waves = 2M x 4N, per-wave 128x64).
// One __syncthreads per K-step; staging issued at step top, drained by the
// barrier a full step later (drain is free). 96 MFMA per wave per step.
__launch_bounds__(512, 2)
__global__ void k_gemm256(const us8* __restrict__ xpk, const us8* __restrict__ wpk,
                          const float* __restrict__ w2, u64* __restrict__ keys) {
    __shared__ us8 lds[2][ASLOT + BSLOT];   // 128 KB

    const int blk = blockIdx.x;
    // XCD-chunked (1024 % 8 == 0, bijective): XCD c owns gy in [c*32, c*32+32),
    // the 4 gx-blocks of each gy adjacent.
    const int gy = (blk & 7) * 32 + (blk >> 5);
    const int gx = (blk >> 3) & 3;
    const int t = threadIdx.x;
    const int lane = t & 63;
    const int wv = t >> 6;
    const int wm = wv >> 2;      // 0..1 (128 rows each)
    const int wn = wv & 3;       // 0..3 (64 cols each)

    const us8* asrc = xpk + (size_t)gy * (NKT * ASLOT);
    const us8* bsrc = wpk + (size_t)gx * (NKT * BSLOT);

    auto stage = [&](int buf, int tk) {
        const us8* sa = asrc + tk * ASLOT;
        const us8* sb = bsrc + tk * BSLOT;
#pragma unroll
        for (int i = 0; i < 4; ++i) gl16(sa + i * 512 + t, &lds[buf][i * 512 + t]);
#pragma unroll
        for (int i = 0; i < 4; ++i) gl16(sb + i * 512 + t, &lds[buf][ASLOT + i * 512 + t]);
    };

    f32x4 acc[8][4];
#pragma unroll
    for (int i = 0; i < 8; ++i)
#pragma unroll
        for (int j = 0; j < 4; ++j) acc[i][j] = (f32x4){0.f, 0.f, 0.f, 0.f};

    stage(0, 0);
    __syncthreads();

    for (int tk = 0; tk < NKT; ++tk) {
        const int buf = tk & 1;
        if (tk + 1 < NKT) stage(buf ^ 1, tk + 1);

        const us8* A = &lds[buf][0];
        const us8* B = &lds[buf][ASLOT];

        bf16x8 bh[4], bl[4];
#pragma unroll
        for (int ct = 0; ct < 4; ++ct) {
            const int o = (wn * 4 + ct) * 128 + lane;
            bh[ct] = __builtin_bit_cast(bf16x8, B[o]);
            bl[ct] = __builtin_bit_cast(bf16x8, B[o + 64]);
        }
#pragma unroll
        for (int p = 0; p < 4; ++p) {
            bf16x8 ah[2], al[2];
#pragma unroll
            for (int i = 0; i < 2; ++i) {
                const int o = (wm * 8 + p * 2 + i) * 128 + lane;
                ah[i] = __builtin_bit_cast(bf16x8, A[o]);
                al[i] = __builtin_bit_cast(bf16x8, A[o + 64]);
            }
#pragma unroll
            for (int i = 0; i < 2; ++i)
#pragma unroll
                for (int ct = 0; ct < 4; ++ct) {
                    const int m = p * 2 + i;
                    acc[m][ct] = __builtin_amdgcn_mfma_f32_16x16x32_bf16(ah[i], bh[ct], acc[m][ct], 0, 0, 0);
                    acc[m][ct] = __builtin_amdgcn_mfma_f32_16x16x32_bf16(ah[i], bl[ct], acc[m][ct], 0, 0, 0);
                    acc[m][ct] = __builtin_amdgcn_mfma_f32_16x16x32_bf16(al[i], bh[ct], acc[m][ct], 0, 0, 0);
                }
        }
        __syncthreads();   // drains staging vmcnt (issued a full step ago) + buf reuse guard
    }

    // epilogue: dist = w2 - 2*dot, per-row argmin, global atomicMin merge
    const int col_base = gx * BN + wn * 64;
    float w2c[4];
#pragma unroll
    for (int ct = 0; ct < 4; ++ct) w2c[ct] = w2[col_base + ct * 16 + (lane & 15)];

#pragma unroll
    for (int rt = 0; rt < 8; ++rt) {
#pragma unroll
        for (int reg = 0; reg < 4; ++reg) {
            u64 km = ~0ull;
#pragma unroll
            for (int ct = 0; ct < 4; ++ct) {
                float dist = w2c[ct] - 2.0f * acc[rt][ct][reg];
                uint su = __float_as_uint(dist);
                su = (su & 0x80000000u) ? ~su : (su | 0x80000000u);
                const int col = col_base + ct * 16 + (lane & 15);
                u64 key = ((u64)su << 32) | (uint)col;
                km = key < km ? key : km;
            }
#pragma unroll
            for (int m = 1; m < 16; m <<= 1) {
                u64 o = __shfl_xor((unsigned long long)km, m);
                km = o < km ? o : km;
            }
            if ((lane & 15) == 0) {
                const int row = gy * BM + wm * 128 + rt * 16 + (lane >> 4) * 4 + reg;
                atomicMin((unsigned long long*)&keys[row], (unsigned long long)km);
            }
        }
    }
}

// ---- fallback GEMM (fully self-contained, reg-staged conversion) ----
__launch_bounds__(256, 2)
__global__ void k_gemm_fb(const float* __restrict__ x, const float* __restrict__ w,
                          const float* __restrict__ w2, u64* __restrict__ keys) {
    __shared__ ushort_t a_lds[2][8][2][64][8];
    __shared__ ushort_t b_lds[2][8][2][64][8];

    const int blk = blockIdx.x;
    const int gx = blk & 7;
    const int gy = blk >> 3;
    const int row0 = gy * 128;
    const int col0 = gx * 128;
    const int t = threadIdx.x;

    const int a_row = t >> 1;
    const int a_j8 = (t & 1) * 2;
    const int b_col = t & 127;
    const int b_j8 = t >> 7;

    float4 aR[4];
    float  bR[16];

    auto stage_load = [&](int ks) {
        const float* ap = x + (size_t)(row0 + a_row) * VEC + ks * 32 + a_j8 * 8;
        aR[0] = *(const float4*)(ap + 0);
        aR[1] = *(const float4*)(ap + 4);
        aR[2] = *(const float4*)(ap + 8);
        aR[3] = *(const float4*)(ap + 12);
        const float* bp = w + (size_t)(ks * 32 + b_j8 * 8) * K + col0 + b_col;
#pragma unroll
        for (int j = 0; j < 8; ++j) bR[j] = bp[(size_t)j * K];
        const float* bp2 = bp + (size_t)16 * K;
#pragma unroll
        for (int j = 0; j < 8; ++j) bR[8 + j] = bp2[(size_t)j * K];
    };

    auto stage_write = [&](int buf) {
        const float* af = (const float*)aR;
        const int slab = a_row >> 4;
#pragma unroll
        for (int c = 0; c < 2; ++c) {
            us8 hi, lo;
#pragma unroll
            for (int j = 0; j < 8; ++j) { hi[j] = hi_of(af[c * 8 + j]); lo[j] = lo_of(af[c * 8 + j]); }
            const int lane = (a_row & 15) | ((a_j8 + c) << 4);
            *(us8*)&a_lds[buf][slab][0][lane][0] = hi;
            *(us8*)&a_lds[buf][slab][1][lane][0] = lo;
        }
        const int ct = b_col >> 4;
#pragma unroll
        for (int c = 0; c < 2; ++c) {
            us8 hi, lo;
#pragma unroll
            for (int j = 0; j < 8; ++j) { hi[j] = hi_of(bR[c * 8 + j]); lo[j] = lo_of(bR[c * 8 + j]); }
            const int lane = (b_col & 15) | ((b_j8 + 2 * c) << 4);
            *(us8*)&b_lds[buf][ct][0][lane][0] = hi;
            *(us8*)&b_lds[buf][ct][1][lane][0] = lo;
        }
    };

    const int wv = t >> 6, lane = t & 63;
    const int wr = wv >> 1, wc = wv & 1;

    f32x4 acc[4][4];
#pragma unroll
    for (int i = 0; i < 4; ++i)
#pragma unroll
        for (int j = 0; j < 4; ++j) acc[i][j] = (f32x4){0.f, 0.f, 0.f, 0.f};

    stage_load(0);
    stage_write(0);
    __syncthreads();

    for (int ks = 0; ks < 16; ++ks) {
        const int buf = ks & 1;
        if (ks + 1 < 16) stage_load(ks + 1);

        bf16x8 ah[4], al[4];
#pragma unroll
        for (int rt = 0; rt < 4; ++rt) {
            ah[rt] = __builtin_bit_cast(bf16x8, *(const us8*)&a_lds[buf][wr * 4 + rt][0][lane][0]);
            al[rt] = __builtin_bit_cast(bf16x8, *(const us8*)&a_lds[buf][wr * 4 + rt][1][lane][0]);
        }
#pragma unroll
        for (int ct = 0; ct < 4; ++ct) {
            bf16x8 bh = __builtin_bit_cast(bf16x8, *(const us8*)&b_lds[buf][wc * 4 + ct][0][lane][0]);
            bf16x8 bl = __builtin_bit_cast(bf16x8, *(const us8*)&b_lds[buf][wc * 4 + ct][1][lane][0]);
#pragma unroll
            for (int rt = 0; rt < 4; ++rt) {
                acc[rt][ct] = __builtin_amdgcn_mfma_f32_16x16x32_bf16(ah[rt], bh, acc[rt][ct], 0, 0, 0);
                acc[rt][ct] = __builtin_amdgcn_mfma_f32_16x16x32_bf16(ah[rt], bl, acc[rt][ct], 0, 0, 0);
                acc[rt][ct] = __builtin_amdgcn_mfma_f32_16x16x32_bf16(al[rt], bh, acc[rt][ct], 0, 0, 0);
            }
        }
        if (ks + 1 < 16) stage_write(buf ^ 1);
        __syncthreads();
    }

    float w2c[4];
#pragma unroll
    for (int ct = 0; ct < 4; ++ct)
        w2c[ct] = w2[col0 + wc * 64 + ct * 16 + (lane & 15)];

#pragma unroll
    for (int rt = 0; rt < 4; ++rt) {
#pragma unroll
        for (int reg = 0; reg < 4; ++reg) {
            u64 km = ~0ull;
#pragma unroll
            for (int ct = 0; ct < 4; ++ct) {
                float dist = w2c[ct] - 2.0f * acc[rt][ct][reg];
                uint su = __float_as_uint(dist);
                su = (su & 0x80000000u) ? ~su : (su | 0x80000000u);
                const int col = col0 + wc * 64 + ct * 16 + (lane & 15);
                u64 key = ((u64)su << 32) | (uint)col;
                km = key < km ? key : km;
            }
#pragma unroll
            for (int m = 1; m < 16; m <<= 1) {
                u64 o = __shfl_xor((unsigned long long)km, m);
                km = o < km ? o : km;
            }
            if ((lane & 15) == 0) {
                const int row = row0 + wr * 64 + rt * 16 + (lane >> 4) * 4 + reg;
                atomicMin((unsigned long long*)&keys[row], (unsigned long long)km);
            }
        }
    }
}

// ---- histogram from keys ----
__global__ void k_hist(const u64* __restrict__ keys, int* __restrict__ counts) {
    const int b = blockIdx.x * blockDim.x + threadIdx.x;
    atomicAdd(&counts[(uint)(keys[b] & 0xffffffffull)], 1);
}

// ---- scan of counts -> offsets; EMA cluster sizes -> cs ----
__global__ void k_scan(const int* __restrict__ counts,
                       const float* __restrict__ cluster_size,
                       int* __restrict__ offsets, float* __restrict__ cs) {
    __shared__ int sa[K];
    __shared__ int sb[K];
    __shared__ float sf[K];
    const int t = threadIdx.x;
    const int c = counts[t];

    sa[t] = c;
    __syncthreads();
    int* src = sa;
    int* dst = sb;
    for (int d = 1; d < K; d <<= 1) {
        dst[t] = src[t] + ((t >= d) ? src[t - d] : 0);
        __syncthreads();
        int* tmp = src; src = dst; dst = tmp;
    }
    offsets[t] = src[t] - c;

    float ncs = GAMMA * cluster_size[t] + (1.0f - GAMMA) * ((c == 0) ? 1.0f : (float)c);
    sf[t] = ncs;
    __syncthreads();
    for (int d = K / 2; d > 0; d >>= 1) {
        if (t < d) sf[t] += sf[t + d];
        __syncthreads();
    }
    float n = sf[0];
    cs[t] = (ncs + EPS) / (n + (float)K * EPS) * n;
}

// ---- counting-sort scatter ----
__global__ void k_scatter(const u64* __restrict__ keys, const int* __restrict__ offsets,
                          int* __restrict__ cursor, int* __restrict__ sorted,
                          int* __restrict__ sortedk) {
    const int b = blockIdx.x * blockDim.x + threadIdx.x;
    const int k = (int)(uint)(keys[b] & 0xffffffffull);
    const int pos = atomicAdd(&cursor[k], 1);
    sorted[offsets[k] + pos] = b;
    sortedk[offsets[k] + pos] = k;
}

// ---- balanced segmented reduction: 64 sorted rows per block ----
__launch_bounds__(512)
__global__ void k_segred(const float* __restrict__ x, const int* __restrict__ sorted,
                         const int* __restrict__ sortedk, float* __restrict__ esum) {
    __shared__ int srow[SEG];
    __shared__ int skid[SEG];
    const int b = blockIdx.x;
    const int t = threadIdx.x;
    if (t < SEG) {
        srow[t] = sorted[b * SEG + t];
        skid[t] = sortedk[b * SEG + t];
    }
    __syncthreads();

    float a = 0.f;
    int cur = skid[0];
#pragma unroll 8
    for (int i = 0; i < SEG; ++i) {
        const int k = skid[i];
        if (k != cur) {
            atomicAdd(&esum[(size_t)cur * VEC + t], a);
            a = 0.f;
            cur = k;
        }
        a += x[(size_t)srow[i] * VEC + t];
    }
    atomicAdd(&esum[(size_t)cur * VEC + t], a);
}

// ---- finalize: transpose esum (K,VEC)->(VEC,K), EMA + normalize ----
__launch_bounds__(256)
__global__ void k_finalize(const float* __restrict__ esum, const float* __restrict__ embed_avg,
                           const float* __restrict__ cs, float* __restrict__ out) {
    __shared__ float tile[64][65];
    const int k0 = blockIdx.x * 64;
    const int v0 = blockIdx.y * 64;
    const int c = threadIdx.x & 63;
    const int r0 = threadIdx.x >> 6;
#pragma unroll
    for (int j = 0; j < 16; ++j) {
        const int r = r0 + j * 4;
        tile[r][c] = esum[(size_t)(k0 + r) * VEC + v0 + c];
    }
    __syncthreads();
    const float csk = cs[k0 + c];
#pragma unroll
    for (int j = 0; j < 16; ++j) {
        const int r = r0 + j * 4;
        const size_t o = (size_t)(v0 + r) * K + k0 + c;
        out[o] = (GAMMA * embed_avg[o] + (1.0f - GAMMA) * tile[c][r]) / csk;
    }
}

extern "C" void kernel_launch(void* const* d_in, const int* in_sizes, int n_in,
                              void* d_out, int out_size, void* d_ws, size_t ws_size,
                              hipStream_t stream) {
    const float* x            = (const float*)d_in[0];   // (BATCH, VEC)
    const float* w            = (const float*)d_in[1];   // (VEC, K)
    const float* cluster_size = (const float*)d_in[2];   // (K,)
    const float* embed_avg    = (const float*)d_in[3];   // (VEC, K)
    float* out = (float*)d_out;                          // (VEC, K)

    // ws: keys | w2 | cs | counts | cursor | offsets | sorted | sortedk | esum | wpk | xpk
    u64*   keys    = (u64*)d_ws;
    float* w2      = (float*)(keys + BATCH);
    float* cs      = w2 + K;
    int*   counts  = (int*)(cs + K);
    int*   cursor  = counts + K;
    int*   offsets = cursor + K;
    int*   sorted  = offsets + K;
    int*   sortedk = sorted + BATCH;
    float* esum    = (float*)(sortedk + BATCH);          // (K, VEC), 2 MB
    us8*   wpk     = (us8*)(esum + (size_t)K * VEC);     // 2 MB (64 groups x 2048)
    us8*   xpk     = wpk + (size_t)64 * BSLOT;           // 128 MB (256 groups x 32768)
    const size_t need_apk = (size_t)((char*)(xpk + (size_t)256 * (NKT * ASLOT)) - (char*)d_ws);
    const bool apk = (ws_size >= need_apk);

    hipMemsetAsync(keys, 0xFF, (size_t)BATCH * sizeof(u64), stream);
    hipMemsetAsync(counts, 0, 2 * K * sizeof(int), stream);          // counts + cursor
    hipMemsetAsync(esum, 0, (size_t)K * VEC * sizeof(float), stream);

    k_w2<<<K / 16, 256, 0, stream>>>(w, w2);
    if (apk) {
        k_pack_w<<<64, 256, 0, stream>>>(w, wpk);
        k_pack_x<<<2048, 256, 0, stream>>>(x, xpk);
        k_gemm256<<<(BATCH / BM) * (K / BN), 512, 0, stream>>>(xpk, wpk, w2, keys);
    } else {
        k_gemm_fb<<<(BATCH / 128) * (K / 128), 256, 0, stream>>>(x, w, w2, keys);
    }
    k_hist<<<BATCH / 256, 256, 0, stream>>>(keys, counts);
    k_scan<<<1, K, 0, stream>>>(counts, cluster_size, offsets, cs);
    k_scatter<<<BATCH / 256, 256, 0, stream>>>(keys, offsets, cursor, sorted, sortedk);
    k_segred<<<BATCH / SEG, 512, 0, stream>>>(x, sorted, sortedk, esum);
    k_finalize<<<dim3(K / 64, VEC / 64), 256, 0, stream>>>(esum, embed_avg, cs, out);
}

// Round 7
// 462.599 us; speedup vs baseline: 1.2732x; 1.0761x over previous
//
#include <hip/hip_runtime.h>

typedef unsigned int uint;
typedef unsigned short ushort_t;
typedef unsigned long long u64;
typedef __attribute__((ext_vector_type(4))) float f32x4;
typedef __attribute__((ext_vector_type(8))) __bf16 bf16x8;
typedef __attribute__((ext_vector_type(8))) unsigned short us8;

#define BATCH 65536
#define VEC 512
#define K 1024
#define GAMMA 0.99f
#define EPS 1e-05f
#define SEG 64

// GEMM geometry: 256x256 tile, 8 waves (2M x 4N), per-wave 128x64, BK=32
#define BM 256
#define BN 256
#define NKT (VEC / 32)      // 16 K-tiles
#define BSLOT 2048          // us8 granules per B K-tile (256 cols x 32k x hi/lo)

__device__ __forceinline__ ushort_t hi_of(float f) {
    return (ushort_t)(__float_as_uint(f) >> 16);
}
__device__ __forceinline__ ushort_t lo_of(float f) {
    float fhi = __uint_as_float(__float_as_uint(f) & 0xffff0000u);
    return (ushort_t)(__float_as_uint(f - fhi) >> 16);
}

__device__ __forceinline__ void gl16(const void* g, void* l) {
    __builtin_amdgcn_global_load_lds(
        (const __attribute__((address_space(1))) unsigned int*)g,
        (__attribute__((address_space(3))) unsigned int*)l, 16, 0, 0);
}

// split 8 f32 (two quads) -> hi/lo bf16x8; bit-identical to the packed path
__device__ __forceinline__ void cvt8(f32x4 q0, f32x4 q1, bf16x8& h, bf16x8& l) {
    float ff[8] = {q0[0], q0[1], q0[2], q0[3], q1[0], q1[1], q1[2], q1[3]};
    us8 hh, ll;
#pragma unroll
    for (int j = 0; j < 8; ++j) {
        hh[j] = hi_of(ff[j]);
        ll[j] = lo_of(ff[j]);
    }
    h = __builtin_bit_cast(bf16x8, hh);
    l = __builtin_bit_cast(bf16x8, ll);
}

// ---- column norms of weight (VEC,K) ----
__global__ void k_w2(const float* __restrict__ w, float* __restrict__ w2) {
    __shared__ float red[16][17];
    const int c = blockIdx.x * 16 + (threadIdx.x & 15);
    const int vg = threadIdx.x >> 4;
    float s = 0.f;
    for (int i = 0; i < 32; ++i) {
        float t = w[(size_t)(vg * 32 + i) * K + c];
        s += t * t;
    }
    red[vg][threadIdx.x & 15] = s;
    __syncthreads();
    if (vg == 0) {
        float acc = 0.f;
#pragma unroll
        for (int g = 0; g < 16; ++g) acc += red[g][threadIdx.x & 15];
        w2[c] = acc;
    }
}

// ---- pack w into B granules: [gx 4][ks 16][ct 16][half 2][lane 64] us8 ----
__global__ void k_pack_w(const float* __restrict__ w, us8* __restrict__ wpk) {
    const int g = blockIdx.x;            // gx*16 + ks, 64 blocks
    const int gx = g >> 4, ks = g & 15;
    const int t = threadIdx.x;
    us8* dst = wpk + (size_t)g * BSLOT;
#pragma unroll
    for (int i = 0; i < 8; ++i) {
        const int o = i * 256 + t;       // 0..2047
        const int lane = o & 63, half = (o >> 6) & 1, ct = o >> 7;
        const int col = gx * BN + ct * 16 + (lane & 15);
        const int kb = ks * 32 + (lane >> 4) * 8;
        us8 v;
#pragma unroll
        for (int j = 0; j < 8; ++j) {
            float f = w[(size_t)(kb + j) * K + col];
            v[j] = half ? lo_of(f) : hi_of(f);
        }
        dst[o] = v;
    }
}

// ---- main: 256x256 split-bf16 MFMA distance GEMM + per-row argmin merge ----
// A staged DIRECTLY from x (f32) via global_load_lds in fragment-granule order:
//   g16 = slab*128 + khalf*64 + lane ; row = gy*256+slab*16+(lane&15),
//   k = kt*32 + (lane>>4)*8 + khalf*4. Conversion to hi/lo bf16 happens in
//   registers after ds_read (bit-identical to the old packed path).
__launch_bounds__(512, 2)
__global__ void k_gemm256(const float* __restrict__ x, const us8* __restrict__ wpk,
                          const float* __restrict__ w2, u64* __restrict__ keys) {
    __shared__ us8 lds[2][4096];   // [0..2047]=A f32 granules, [2048..4095]=B; 128 KB

    const int blk = blockIdx.x;
    // XCD-chunked bijection (1024 % 8 == 0): XCD c owns gy in [c*32, c*32+32),
    // the 4 gx-blocks of each gy dispatched adjacently -> A-tile L2 reuse.
    const int gy = (blk & 7) * 32 + (blk >> 5);
    const int gx = (blk >> 3) & 3;
    const int t = threadIdx.x;
    const int lane = t & 63;
    const int wv = t >> 6;
    const int wm = wv >> 2;      // 0..1 (128 rows each)
    const int wn = wv & 3;       // 0..3 (64 cols each)

    const us8* bsrc = wpk + (size_t)gx * (NKT * BSLOT);

    auto stage = [&](int buf, int kt) {
#pragma unroll
        for (int i = 0; i < 4; ++i) {
            const int g16 = i * 512 + t;
            const int slab = g16 >> 7, kh = (g16 >> 6) & 1, l = g16 & 63;
            const int row = gy * BM + slab * 16 + (l & 15);
            const int k = kt * 32 + ((l >> 4) << 3) + (kh << 2);
            gl16(x + (size_t)row * VEC + k, &lds[buf][g16]);
        }
        const us8* sb = bsrc + (size_t)kt * BSLOT;
#pragma unroll
        for (int i = 0; i < 4; ++i)
            gl16(sb + i * 512 + t, &lds[buf][2048 + i * 512 + t]);
    };

    f32x4 acc[8][4];
#pragma unroll
    for (int i = 0; i < 8; ++i)
#pragma unroll
        for (int j = 0; j < 4; ++j) acc[i][j] = (f32x4){0.f, 0.f, 0.f, 0.f};

    stage(0, 0);
    __syncthreads();

    for (int tk = 0; tk < NKT; ++tk) {
        const int buf = tk & 1;
        if (tk + 1 < NKT) stage(buf ^ 1, tk + 1);

        const us8* A = &lds[buf][0];
        const us8* B = &lds[buf][2048];

        bf16x8 bh[4], bl[4];
#pragma unroll
        for (int ct = 0; ct < 4; ++ct) {
            const int o = (wn * 4 + ct) * 128 + lane;
            bh[ct] = __builtin_bit_cast(bf16x8, B[o]);
            bl[ct] = __builtin_bit_cast(bf16x8, B[o + 64]);
        }
#pragma unroll
        for (int p = 0; p < 4; ++p) {
            bf16x8 ah[2], al[2];
#pragma unroll
            for (int i = 0; i < 2; ++i) {
                const int slab = wm * 8 + p * 2 + i;
                f32x4 q0 = __builtin_bit_cast(f32x4, A[slab * 128 + lane]);
                f32x4 q1 = __builtin_bit_cast(f32x4, A[slab * 128 + 64 + lane]);
                cvt8(q0, q1, ah[i], al[i]);
            }
#pragma unroll
            for (int i = 0; i < 2; ++i)
#pragma unroll
                for (int ct = 0; ct < 4; ++ct) {
                    const int m = p * 2 + i;
                    acc[m][ct] = __builtin_amdgcn_mfma_f32_16x16x32_bf16(ah[i], bh[ct], acc[m][ct], 0, 0, 0);
                    acc[m][ct] = __builtin_amdgcn_mfma_f32_16x16x32_bf16(ah[i], bl[ct], acc[m][ct], 0, 0, 0);
                    acc[m][ct] = __builtin_amdgcn_mfma_f32_16x16x32_bf16(al[i], bh[ct], acc[m][ct], 0, 0, 0);
                }
        }
        __syncthreads();   // drains staging (issued a full step earlier) + buf guard
    }

    // epilogue: dist = w2 - 2*dot, per-row argmin, global atomicMin merge
    const int col_base = gx * BN + wn * 64;
    float w2c[4];
#pragma unroll
    for (int ct = 0; ct < 4; ++ct) w2c[ct] = w2[col_base + ct * 16 + (lane & 15)];

#pragma unroll
    for (int rt = 0; rt < 8; ++rt) {
#pragma unroll
        for (int reg = 0; reg < 4; ++reg) {
            u64 km = ~0ull;
#pragma unroll
            for (int ct = 0; ct < 4; ++ct) {
                float dist = w2c[ct] - 2.0f * acc[rt][ct][reg];
                uint su = __float_as_uint(dist);
                su = (su & 0x80000000u) ? ~su : (su | 0x80000000u);
                const int col = col_base + ct * 16 + (lane & 15);
                u64 key = ((u64)su << 32) | (uint)col;
                km = key < km ? key : km;
            }
#pragma unroll
            for (int m = 1; m < 16; m <<= 1) {
                u64 o = __shfl_xor((unsigned long long)km, m);
                km = o < km ? o : km;
            }
            if ((lane & 15) == 0) {
                const int row = gy * BM + wm * 128 + rt * 16 + (lane >> 4) * 4 + reg;
                atomicMin((unsigned long long*)&keys[row], (unsigned long long)km);
            }
        }
    }
}

// ---- histogram from keys ----
__global__ void k_hist(const u64* __restrict__ keys, int* __restrict__ counts) {
    const int b = blockIdx.x * blockDim.x + threadIdx.x;
    atomicAdd(&counts[(uint)(keys[b] & 0xffffffffull)], 1);
}

// ---- scan of counts -> offsets; EMA cluster sizes -> cs (wave-shuffle) ----
__global__ void k_scan(const int* __restrict__ counts,
                       const float* __restrict__ cluster_size,
                       int* __restrict__ offsets, float* __restrict__ cs) {
    __shared__ int wsum[16];
    __shared__ float fw[16];
    const int t = threadIdx.x;           // 0..1023
    const int lane = t & 63, wid = t >> 6;
    const int c = counts[t];

    // inclusive wave scan
    int s = c;
#pragma unroll
    for (int d = 1; d < 64; d <<= 1) {
        int o = __shfl_up(s, d);
        if (lane >= d) s += o;
    }
    // EMA + wave sum (float)
    float ncs = GAMMA * cluster_size[t] + (1.0f - GAMMA) * ((c == 0) ? 1.0f : (float)c);
    float fs = ncs;
#pragma unroll
    for (int d = 32; d > 0; d >>= 1) fs += __shfl_xor(fs, d);

    if (lane == 63) wsum[wid] = s;
    if (lane == 0) fw[wid] = fs;
    __syncthreads();
    if (wid == 0 && lane < 16) {
        int v = wsum[lane];
#pragma unroll
        for (int d = 1; d < 16; d <<= 1) {
            int o = __shfl_up(v, d);
            if (lane >= d) v += o;
        }
        wsum[lane] = v;
    }
    __syncthreads();
    const int base = wid ? wsum[wid - 1] : 0;
    offsets[t] = base + s - c;           // exclusive scan

    float n = 0.f;
#pragma unroll
    for (int i = 0; i < 16; ++i) n += fw[i];
    cs[t] = (ncs + EPS) / (n + (float)K * EPS) * n;
}

// ---- counting-sort scatter ----
__global__ void k_scatter(const u64* __restrict__ keys, const int* __restrict__ offsets,
                          int* __restrict__ cursor, int* __restrict__ sorted,
                          int* __restrict__ sortedk) {
    const int b = blockIdx.x * blockDim.x + threadIdx.x;
    const int k = (int)(uint)(keys[b] & 0xffffffffull);
    const int pos = atomicAdd(&cursor[k], 1);
    sorted[offsets[k] + pos] = b;
    sortedk[offsets[k] + pos] = k;
}

// ---- balanced segmented reduction: 64 sorted rows per block ----
__launch_bounds__(512)
__global__ void k_segred(const float* __restrict__ x, const int* __restrict__ sorted,
                         const int* __restrict__ sortedk, float* __restrict__ esum) {
    __shared__ int srow[SEG];
    __shared__ int skid[SEG];
    const int b = blockIdx.x;
    const int t = threadIdx.x;
    if (t < SEG) {
        srow[t] = sorted[b * SEG + t];
        skid[t] = sortedk[b * SEG + t];
    }
    __syncthreads();

    float a = 0.f;
    int cur = skid[0];
#pragma unroll 8
    for (int i = 0; i < SEG; ++i) {
        const int k = skid[i];
        if (k != cur) {
            atomicAdd(&esum[(size_t)cur * VEC + t], a);
            a = 0.f;
            cur = k;
        }
        a += x[(size_t)srow[i] * VEC + t];
    }
    atomicAdd(&esum[(size_t)cur * VEC + t], a);
}

// ---- finalize: transpose esum (K,VEC)->(VEC,K), EMA + normalize ----
__launch_bounds__(256)
__global__ void k_finalize(const float* __restrict__ esum, const float* __restrict__ embed_avg,
                           const float* __restrict__ cs, float* __restrict__ out) {
    __shared__ float tile[64][65];
    const int k0 = blockIdx.x * 64;
    const int v0 = blockIdx.y * 64;
    const int c = threadIdx.x & 63;
    const int r0 = threadIdx.x >> 6;
#pragma unroll
    for (int j = 0; j < 16; ++j) {
        const int r = r0 + j * 4;
        tile[r][c] = esum[(size_t)(k0 + r) * VEC + v0 + c];
    }
    __syncthreads();
    const float csk = cs[k0 + c];
#pragma unroll
    for (int j = 0; j < 16; ++j) {
        const int r = r0 + j * 4;
        const size_t o = (size_t)(v0 + r) * K + k0 + c;
        out[o] = (GAMMA * embed_avg[o] + (1.0f - GAMMA) * tile[c][r]) / csk;
    }
}

extern "C" void kernel_launch(void* const* d_in, const int* in_sizes, int n_in,
                              void* d_out, int out_size, void* d_ws, size_t ws_size,
                              hipStream_t stream) {
    const float* x            = (const float*)d_in[0];   // (BATCH, VEC)
    const float* w            = (const float*)d_in[1];   // (VEC, K)
    const float* cluster_size = (const float*)d_in[2];   // (K,)
    const float* embed_avg    = (const float*)d_in[3];   // (VEC, K)
    float* out = (float*)d_out;                          // (VEC, K)

    // ws: keys | w2 | cs | counts | cursor | offsets | sorted | sortedk | esum | wpk (~7 MB)
    u64*   keys    = (u64*)d_ws;
    float* w2      = (float*)(keys + BATCH);
    float* cs      = w2 + K;
    int*   counts  = (int*)(cs + K);
    int*   cursor  = counts + K;
    int*   offsets = cursor + K;
    int*   sorted  = offsets + K;
    int*   sortedk = sorted + BATCH;
    float* esum    = (float*)(sortedk + BATCH);          // (K, VEC), 2 MB
    us8*   wpk     = (us8*)(esum + (size_t)K * VEC);     // 2 MB (64 groups x 2048)

    hipMemsetAsync(keys, 0xFF, (size_t)BATCH * sizeof(u64), stream);
    hipMemsetAsync(counts, 0, 2 * K * sizeof(int), stream);          // counts + cursor
    hipMemsetAsync(esum, 0, (size_t)K * VEC * sizeof(float), stream);

    k_w2<<<K / 16, 256, 0, stream>>>(w, w2);
    k_pack_w<<<64, 256, 0, stream>>>(w, wpk);
    k_gemm256<<<(BATCH / BM) * (K / BN), 512, 0, stream>>>(x, wpk, w2, keys);
    k_hist<<<BATCH / 256, 256, 0, stream>>>(keys, counts);
    k_scan<<<1, K, 0, stream>>>(counts, cluster_size, offsets, cs);
    k_scatter<<<BATCH / 256, 256, 0, stream>>>(keys, offsets, cursor, sorted, sortedk);
    k_segred<<<BATCH / SEG, 512, 0, stream>>>(x, sorted, sortedk, esum);
    k_finalize<<<dim3(K / 64, VEC / 64), 256, 0, stream>>>(esum, embed_avg, cs, out);
}

// Round 8
// 455.780 us; speedup vs baseline: 1.2923x; 1.0150x over previous
//
#include <hip/hip_runtime.h>

typedef unsigned int uint;
typedef unsigned short ushort_t;
typedef unsigned long long u64;
typedef __attribute__((ext_vector_type(4))) float f32x4;
typedef __attribute__((ext_vector_type(8))) __bf16 bf16x8;
typedef __attribute__((ext_vector_type(8))) unsigned short us8;

#define BATCH 65536
#define VEC 512
#define K 1024
#define GAMMA 0.99f
#define EPS 1e-05f
#define SEG 64

// GEMM geometry: 256x256 tile, 8 waves (2M x 4N), per-wave 128x64, BK=32
#define BM 256
#define BN 256
#define NKT (VEC / 32)      // 16 K-tiles
#define BSLOT 2048          // us8 granules per B K-tile (256 cols x 32k x hi/lo)

__device__ __forceinline__ ushort_t hi_of(float f) {
    return (ushort_t)(__float_as_uint(f) >> 16);
}
__device__ __forceinline__ ushort_t lo_of(float f) {
    float fhi = __uint_as_float(__float_as_uint(f) & 0xffff0000u);
    return (ushort_t)(__float_as_uint(f - fhi) >> 16);
}

__device__ __forceinline__ void gl16(const void* g, void* l) {
    __builtin_amdgcn_global_load_lds(
        (const __attribute__((address_space(1))) unsigned int*)g,
        (__attribute__((address_space(3))) unsigned int*)l, 16, 0, 0);
}

// split 8 f32 -> hi/lo bf16x8; bit-identical to all prior rounds
__device__ __forceinline__ void cvt8(f32x4 q0, f32x4 q1, bf16x8& h, bf16x8& l) {
    float ff[8] = {q0[0], q0[1], q0[2], q0[3], q1[0], q1[1], q1[2], q1[3]};
    us8 hh, ll;
#pragma unroll
    for (int j = 0; j < 8; ++j) {
        hh[j] = hi_of(ff[j]);
        ll[j] = lo_of(ff[j]);
    }
    h = __builtin_bit_cast(bf16x8, hh);
    l = __builtin_bit_cast(bf16x8, ll);
}

// ---- pack w (coalesced LDS transpose) + w2 partials + buffer inits ----
// grid 64 blocks (gx 4 x ks 16) x 256 thr.
__global__ void k_pack_w(const float* __restrict__ w, us8* __restrict__ wpk,
                         float* __restrict__ w2p, u64* __restrict__ keys,
                         int* __restrict__ cc /*counts+cursor, 2K ints*/) {
    __shared__ float lds[32][257];
    const int g = blockIdx.x;
    const int gx = g >> 4, ks = g & 15;
    const int t = threadIdx.x;

    // coalesced 32x256 tile load (1KB per instruction)
#pragma unroll
    for (int r = 0; r < 32; ++r)
        lds[r][t] = w[(size_t)(ks * 32 + r) * K + gx * 256 + t];
    __syncthreads();

    // w2 partial for this ks-slice (deterministic: one writer per entry)
    float s = 0.f;
#pragma unroll
    for (int r = 0; r < 32; ++r) { float f = lds[r][t]; s += f * f; }
    w2p[ks * K + gx * 256 + t] = s;

    // pack granules: [ct 16][half 2][lane 64]
#pragma unroll
    for (int i = 0; i < 8; ++i) {
        const int o = i * 256 + t;
        const int lane = o & 63, half = (o >> 6) & 1, ct = o >> 7;
        const int cl = ct * 16 + (lane & 15);
        const int r0 = (lane >> 4) * 8;
        us8 v;
#pragma unroll
        for (int j = 0; j < 8; ++j) {
            float f = lds[r0 + j][cl];
            v[j] = half ? lo_of(f) : hi_of(f);
        }
        wpk[(size_t)g * BSLOT + o] = v;
    }

    // buffer inits (replaces 2 memsets + spreads work)
    u64* kp = keys + (size_t)g * 1024;
#pragma unroll
    for (int i = 0; i < 4; ++i) kp[i * 256 + t] = ~0ull;
    if (g < 8) cc[g * 256 + t] = 0;
}

// ---- main: 256x256 split-bf16 MFMA distance GEMM + per-row argmin merge ----
// A reg-staged from x with cvt-on-stage (each element converted once/block);
// B via global_load_lds from packed wpk. One barrier per K-step.
__launch_bounds__(512, 2)
__global__ void k_gemm256(const float* __restrict__ x, const us8* __restrict__ wpk,
                          const float* __restrict__ w2p, u64* __restrict__ keys) {
    __shared__ us8 a_lds[2][2048];   // 256 rows x 32k hi/lo bf16, 32KB/buf
    __shared__ us8 b_lds[2][2048];   // 256 cols x 32k hi/lo bf16, 32KB/buf

    const int blk = blockIdx.x;
    // XCD-chunked bijection (1024 % 8 == 0): XCD c owns gy in [c*32, c*32+32);
    // the 4 gx-blocks of each gy run consecutively on that XCD -> A L2 reuse.
    const int gy = (blk & 7) * 32 + (blk >> 5);
    const int gx = (blk >> 3) & 3;
    const int t = threadIdx.x;
    const int lane = t & 63;
    const int wv = t >> 6;
    const int wm = wv >> 2;      // 0..1 (128 rows)
    const int wn = wv & 3;       // 0..3 (64 cols)

    const us8* bsrc = wpk + (size_t)gx * (NKT * BSLOT);

    // A staging identities: thread t owns granule-pairs (slab0, t&63) and (slab0+8, t&63)
    const int slab0 = t >> 6;                 // 0..7
    const int ls = t & 63;                    // (kgrp<<4)|row_in_slab
    const float* xrow0 = x + (size_t)(gy * BM + slab0 * 16 + (ls & 15)) * VEC + (ls >> 4) * 8;
    const float* xrow1 = xrow0 + (size_t)128 * VEC;

    f32x4 av[4];
    auto aload = [&](int kt) {
        const float* p0 = xrow0 + kt * 32;
        av[0] = *(const f32x4*)(p0);
        av[1] = *(const f32x4*)(p0 + 4);
        const float* p1 = xrow1 + kt * 32;
        av[2] = *(const f32x4*)(p1);
        av[3] = *(const f32x4*)(p1 + 4);
    };
    auto awrite = [&](int buf) {
        bf16x8 h0, l0, h1, l1;
        cvt8(av[0], av[1], h0, l0);
        cvt8(av[2], av[3], h1, l1);
        const int o = slab0 * 128 + ls;
        a_lds[buf][o]          = __builtin_bit_cast(us8, h0);
        a_lds[buf][o + 64]     = __builtin_bit_cast(us8, l0);
        a_lds[buf][o + 1024]       = __builtin_bit_cast(us8, h1);
        a_lds[buf][o + 1024 + 64]  = __builtin_bit_cast(us8, l1);
    };
    auto bstage = [&](int buf, int kt) {
        const us8* sb = bsrc + (size_t)kt * BSLOT;
#pragma unroll
        for (int i = 0; i < 4; ++i)
            gl16(sb + i * 512 + t, &b_lds[buf][i * 512 + t]);
    };

    f32x4 acc[8][4];
#pragma unroll
    for (int i = 0; i < 8; ++i)
#pragma unroll
        for (int j = 0; j < 4; ++j) acc[i][j] = (f32x4){0.f, 0.f, 0.f, 0.f};

    aload(0);
    bstage(0, 0);
    awrite(0);
    __syncthreads();

    for (int tk = 0; tk < NKT; ++tk) {
        const int buf = tk & 1;
        const bool nx = (tk + 1 < NKT);
        if (nx) {                       // issue next-tile loads early (T14)
            aload(tk + 1);
            bstage(buf ^ 1, tk + 1);
        }

        const us8* A = &a_lds[buf][0];
        const us8* B = &b_lds[buf][0];

        bf16x8 bh[4], bl[4];
#pragma unroll
        for (int ct = 0; ct < 4; ++ct) {
            const int o = (wn * 4 + ct) * 128 + lane;
            bh[ct] = __builtin_bit_cast(bf16x8, B[o]);
            bl[ct] = __builtin_bit_cast(bf16x8, B[o + 64]);
        }
#pragma unroll
        for (int p = 0; p < 4; ++p) {
            bf16x8 ah[2], al[2];
#pragma unroll
            for (int i = 0; i < 2; ++i) {
                const int o = (wm * 8 + p * 2 + i) * 128 + lane;
                ah[i] = __builtin_bit_cast(bf16x8, A[o]);
                al[i] = __builtin_bit_cast(bf16x8, A[o + 64]);
            }
#pragma unroll
            for (int i = 0; i < 2; ++i)
#pragma unroll
                for (int ct = 0; ct < 4; ++ct) {
                    const int m = p * 2 + i;
                    acc[m][ct] = __builtin_amdgcn_mfma_f32_16x16x32_bf16(ah[i], bh[ct], acc[m][ct], 0, 0, 0);
                    acc[m][ct] = __builtin_amdgcn_mfma_f32_16x16x32_bf16(ah[i], bl[ct], acc[m][ct], 0, 0, 0);
                    acc[m][ct] = __builtin_amdgcn_mfma_f32_16x16x32_bf16(al[i], bh[ct], acc[m][ct], 0, 0, 0);
                }
        }
        if (nx) awrite(buf ^ 1);        // cvt + ds_write late (loads have landed)
        __syncthreads();                // drains vmcnt (B gl16) + lgkm, buf guard
    }

    // epilogue: w2 from partials, dist = w2 - 2*dot, argmin, atomicMin merge
    const int col_base = gx * BN + wn * 64;
    float w2c[4];
#pragma unroll
    for (int ct = 0; ct < 4; ++ct) {
        const int col = col_base + ct * 16 + (lane & 15);
        float s = 0.f;
#pragma unroll
        for (int p = 0; p < 16; ++p) s += w2p[p * K + col];
        w2c[ct] = s;
    }

#pragma unroll
    for (int rt = 0; rt < 8; ++rt) {
#pragma unroll
        for (int reg = 0; reg < 4; ++reg) {
            u64 km = ~0ull;
#pragma unroll
            for (int ct = 0; ct < 4; ++ct) {
                float dist = w2c[ct] - 2.0f * acc[rt][ct][reg];
                uint su = __float_as_uint(dist);
                su = (su & 0x80000000u) ? ~su : (su | 0x80000000u);
                const int col = col_base + ct * 16 + (lane & 15);
                u64 key = ((u64)su << 32) | (uint)col;
                km = key < km ? key : km;
            }
#pragma unroll
            for (int m = 1; m < 16; m <<= 1) {
                u64 o = __shfl_xor((unsigned long long)km, m);
                km = o < km ? o : km;
            }
            if ((lane & 15) == 0) {
                const int row = gy * BM + wm * 128 + rt * 16 + (lane >> 4) * 4 + reg;
                atomicMin((unsigned long long*)&keys[row], (unsigned long long)km);
            }
        }
    }
}

// ---- histogram from keys (+ zero esum for segred) ----
__global__ void k_hist(const u64* __restrict__ keys, int* __restrict__ counts,
                       float* __restrict__ esum) {
    const int b = blockIdx.x * blockDim.x + threadIdx.x;
    f32x4 z = {0.f, 0.f, 0.f, 0.f};
    ((f32x4*)esum)[b * 2]     = z;
    ((f32x4*)esum)[b * 2 + 1] = z;
    atomicAdd(&counts[(uint)(keys[b] & 0xffffffffull)], 1);
}

// ---- scan of counts -> offsets; EMA cluster sizes -> cs (wave-shuffle) ----
__global__ void k_scan(const int* __restrict__ counts,
                       const float* __restrict__ cluster_size,
                       int* __restrict__ offsets, float* __restrict__ cs) {
    __shared__ int wsum[16];
    __shared__ float fw[16];
    const int t = threadIdx.x;           // 0..1023
    const int lane = t & 63, wid = t >> 6;
    const int c = counts[t];

    int s = c;
#pragma unroll
    for (int d = 1; d < 64; d <<= 1) {
        int o = __shfl_up(s, d);
        if (lane >= d) s += o;
    }
    float ncs = GAMMA * cluster_size[t] + (1.0f - GAMMA) * ((c == 0) ? 1.0f : (float)c);
    float fs = ncs;
#pragma unroll
    for (int d = 32; d > 0; d >>= 1) fs += __shfl_xor(fs, d);

    if (lane == 63) wsum[wid] = s;
    if (lane == 0) fw[wid] = fs;
    __syncthreads();
    if (wid == 0 && lane < 16) {
        int v = wsum[lane];
#pragma unroll
        for (int d = 1; d < 16; d <<= 1) {
            int o = __shfl_up(v, d);
            if (lane >= d) v += o;
        }
        wsum[lane] = v;
    }
    __syncthreads();
    const int base = wid ? wsum[wid - 1] : 0;
    offsets[t] = base + s - c;

    float n = 0.f;
#pragma unroll
    for (int i = 0; i < 16; ++i) n += fw[i];
    cs[t] = (ncs + EPS) / (n + (float)K * EPS) * n;
}

// ---- counting-sort scatter ----
__global__ void k_scatter(const u64* __restrict__ keys, const int* __restrict__ offsets,
                          int* __restrict__ cursor, int* __restrict__ sorted,
                          int* __restrict__ sortedk) {
    const int b = blockIdx.x * blockDim.x + threadIdx.x;
    const int k = (int)(uint)(keys[b] & 0xffffffffull);
    const int pos = atomicAdd(&cursor[k], 1);
    sorted[offsets[k] + pos] = b;
    sortedk[offsets[k] + pos] = k;
}

// ---- balanced segmented reduction: 64 sorted rows per block ----
__launch_bounds__(512)
__global__ void k_segred(const float* __restrict__ x, const int* __restrict__ sorted,
                         const int* __restrict__ sortedk, float* __restrict__ esum) {
    __shared__ int srow[SEG];
    __shared__ int skid[SEG];
    const int b = blockIdx.x;
    const int t = threadIdx.x;
    if (t < SEG) {
        srow[t] = sorted[b * SEG + t];
        skid[t] = sortedk[b * SEG + t];
    }
    __syncthreads();

    float a = 0.f;
    int cur = skid[0];
#pragma unroll 8
    for (int i = 0; i < SEG; ++i) {
        const int k = skid[i];
        if (k != cur) {
            atomicAdd(&esum[(size_t)cur * VEC + t], a);
            a = 0.f;
            cur = k;
        }
        a += x[(size_t)srow[i] * VEC + t];
    }
    atomicAdd(&esum[(size_t)cur * VEC + t], a);
}

// ---- finalize: transpose esum (K,VEC)->(VEC,K), EMA + normalize ----
__launch_bounds__(256)
__global__ void k_finalize(const float* __restrict__ esum, const float* __restrict__ embed_avg,
                           const float* __restrict__ cs, float* __restrict__ out) {
    __shared__ float tile[64][65];
    const int k0 = blockIdx.x * 64;
    const int v0 = blockIdx.y * 64;
    const int c = threadIdx.x & 63;
    const int r0 = threadIdx.x >> 6;
#pragma unroll
    for (int j = 0; j < 16; ++j) {
        const int r = r0 + j * 4;
        tile[r][c] = esum[(size_t)(k0 + r) * VEC + v0 + c];
    }
    __syncthreads();
    const float csk = cs[k0 + c];
#pragma unroll
    for (int j = 0; j < 16; ++j) {
        const int r = r0 + j * 4;
        const size_t o = (size_t)(v0 + r) * K + k0 + c;
        out[o] = (GAMMA * embed_avg[o] + (1.0f - GAMMA) * tile[c][r]) / csk;
    }
}

extern "C" void kernel_launch(void* const* d_in, const int* in_sizes, int n_in,
                              void* d_out, int out_size, void* d_ws, size_t ws_size,
                              hipStream_t stream) {
    const float* x            = (const float*)d_in[0];   // (BATCH, VEC)
    const float* w            = (const float*)d_in[1];   // (VEC, K)
    const float* cluster_size = (const float*)d_in[2];   // (K,)
    const float* embed_avg    = (const float*)d_in[3];   // (VEC, K)
    float* out = (float*)d_out;                          // (VEC, K)

    // ws: keys | w2p | cs | counts | cursor | offsets | sorted | sortedk | esum | wpk (~5.1 MB)
    u64*   keys    = (u64*)d_ws;
    float* w2p     = (float*)(keys + BATCH);             // 16 x K partials
    float* cs      = w2p + 16 * K;
    int*   counts  = (int*)(cs + K);
    int*   cursor  = counts + K;
    int*   offsets = cursor + K;
    int*   sorted  = offsets + K;
    int*   sortedk = sorted + BATCH;
    float* esum    = (float*)(sortedk + BATCH);          // (K, VEC), 2 MB
    us8*   wpk     = (us8*)(esum + (size_t)K * VEC);     // 2 MB (64 groups x 2048)

    k_pack_w<<<64, 256, 0, stream>>>(w, wpk, w2p, keys, counts);
    k_gemm256<<<(BATCH / BM) * (K / BN), 512, 0, stream>>>(x, wpk, w2p, keys);
    k_hist<<<BATCH / 256, 256, 0, stream>>>(keys, counts, esum);
    k_scan<<<1, K, 0, stream>>>(counts, cluster_size, offsets, cs);
    k_scatter<<<BATCH / 256, 256, 0, stream>>>(keys, offsets, cursor, sorted, sortedk);
    k_segred<<<BATCH / SEG, 512, 0, stream>>>(x, sorted, sortedk, esum);
    k_finalize<<<dim3(K / 64, VEC / 64), 256, 0, stream>>>(esum, embed_avg, cs, out);
}

// Round 9
// 388.020 us; speedup vs baseline: 1.5179x; 1.1746x over previous
//
#include <hip/hip_runtime.h>

typedef unsigned int uint;
typedef unsigned short ushort_t;
typedef unsigned long long u64;
typedef __attribute__((ext_vector_type(4))) float f32x4;
typedef __attribute__((ext_vector_type(8))) __bf16 bf16x8;
typedef __attribute__((ext_vector_type(8))) unsigned short us8;

#define BATCH 65536
#define VEC 512
#define K 1024
#define GAMMA 0.99f
#define EPS 1e-05f
#define SEG 64
#define MARGIN 0.75f

// GEMM geometry: 128x256 tile, 8 waves (2M x 4N), per-wave 64x64, BK=32
#define NKT (VEC / 32)      // 16 K-tiles

// round-to-nearest-even f32 -> bf16
__device__ __forceinline__ ushort_t rtn(float f) {
    uint u = __float_as_uint(f);
    return (ushort_t)((u + 0x7FFFu + ((u >> 16) & 1u)) >> 16);
}

__device__ __forceinline__ void gl16(const void* g, void* l) {
    __builtin_amdgcn_global_load_lds(
        (const __attribute__((address_space(1))) unsigned int*)g,
        (__attribute__((address_space(3))) unsigned int*)l, 16, 0, 0);
}

__device__ __forceinline__ float dec_key(uint e) {
    uint b = (e & 0x80000000u) ? (e & 0x7FFFFFFFu) : ~e;
    return __uint_as_float(b);
}

// ---- pack w (bf16-rtn granules) + wT (f32 transpose) + w2 partials + inits ----
// grid 64 blocks (gx 4 x ks 16) x 256 thr
__global__ void k_pack_w(const float* __restrict__ w, us8* __restrict__ wpk,
                         float* __restrict__ wT, float* __restrict__ w2p,
                         int* __restrict__ cc /* counts|cursor|listcnt: 2049 ints */) {
    __shared__ float lds[32][257];
    const int g = blockIdx.x;
    const int gx = g >> 4, ks = g & 15;
    const int t = threadIdx.x;

#pragma unroll
    for (int r = 0; r < 32; ++r)
        lds[r][t] = w[(size_t)(ks * 32 + r) * K + gx * 256 + t];
    __syncthreads();

    // w2 partial for this ks-slice
    float s = 0.f;
#pragma unroll
    for (int r = 0; r < 32; ++r) { float f = lds[r][t]; s += f * f; }
    w2p[ks * K + gx * 256 + t] = s;

    // bf16 granules: [ct 16][lane 64], lane=(col&15)|(k8<<4), elems k=k8*8+j
#pragma unroll
    for (int i = 0; i < 4; ++i) {
        const int o = i * 256 + t;
        const int lane = o & 63, ct = o >> 6;
        const int cl = ct * 16 + (lane & 15);
        const int r0 = (lane >> 4) * 8;
        us8 v;
#pragma unroll
        for (int j = 0; j < 8; ++j) v[j] = rtn(lds[r0 + j][cl]);
        wpk[(size_t)g * 1024 + o] = v;
    }

    // wT: (K, VEC) f32 transpose for coalesced per-col reads in recheck
#pragma unroll
    for (int rr = 0; rr < 8; ++rr) {
        f32x4 v = {lds[rr * 4 + 0][t], lds[rr * 4 + 1][t], lds[rr * 4 + 2][t], lds[rr * 4 + 3][t]};
        *(f32x4*)&wT[(size_t)(gx * 256 + t) * VEC + ks * 32 + rr * 4] = v;
    }

    if (g < 8) cc[g * 256 + t] = 0;
    if (g == 8 && t == 0) cc[2048] = 0;
}

// ---- main: 128x256 single-bf16 MFMA distance GEMM, top-2 per row per slot ----
// 2048 blocks x 512 thr; 2 blocks/CU (48KB LDS, <=128 VGPR).
__launch_bounds__(512, 4)
__global__ void k_gemm(const float* __restrict__ x, const us8* __restrict__ wpk,
                       const float* __restrict__ w2p,
                       u64* __restrict__ keysA, u64* __restrict__ keysB) {
    __shared__ us8 a_lds[2][512];    // 128 rows x 32k bf16, 8KB/buf
    __shared__ us8 b_lds[2][1024];   // 256 cols x 32k bf16, 16KB/buf

    const int blk = blockIdx.x;
    // XCD-chunked bijection (2048 % 8 == 0): XCD c owns gy [c*64, c*64+64),
    // the 4 gx of each gy adjacent -> A-tile L2 reuse.
    const int gy = (blk & 7) * 64 + ((blk >> 3) >> 2);
    const int gx = (blk >> 3) & 3;
    const int t = threadIdx.x;
    const int lane = t & 63;
    const int wv = t >> 6;
    const int wm = wv >> 2;      // 0..1 (64 rows)
    const int wn = wv & 3;       // 0..3 (64 cols)

    const us8* bsrc = wpk + (size_t)gx * (NKT * 1024);

    // A staging: thread t owns granule t: slab=t>>6, al=t&63
    const int al = t & 63;
    const float* xp = x + (size_t)(gy * 128 + (t >> 6) * 16 + (al & 15)) * VEC + (al >> 4) * 8;
    f32x4 av0, av1;
    auto aload = [&](int kt) {
        const float* p = xp + kt * 32;
        av0 = *(const f32x4*)p;
        av1 = *(const f32x4*)(p + 4);
    };
    auto awrite = [&](int buf) {
        us8 h;
#pragma unroll
        for (int j = 0; j < 4; ++j) { h[j] = rtn(av0[j]); h[4 + j] = rtn(av1[j]); }
        a_lds[buf][t] = h;
    };
    auto bstage = [&](int buf, int kt) {
        const us8* sb = bsrc + (size_t)kt * 1024;
        gl16(sb + t, &b_lds[buf][t]);
        gl16(sb + 512 + t, &b_lds[buf][512 + t]);
    };

    f32x4 acc[4][4];
#pragma unroll
    for (int i = 0; i < 4; ++i)
#pragma unroll
        for (int j = 0; j < 4; ++j) acc[i][j] = (f32x4){0.f, 0.f, 0.f, 0.f};

    aload(0);
    bstage(0, 0);
    awrite(0);
    __syncthreads();

    for (int tk = 0; tk < NKT; ++tk) {
        const int buf = tk & 1;
        const bool nx = (tk + 1 < NKT);
        if (nx) {
            aload(tk + 1);
            bstage(buf ^ 1, tk + 1);
        }
        bf16x8 bh[4];
#pragma unroll
        for (int ct = 0; ct < 4; ++ct)
            bh[ct] = __builtin_bit_cast(bf16x8, b_lds[buf][(wn * 4 + ct) * 64 + lane]);
#pragma unroll
        for (int rt = 0; rt < 4; ++rt) {
            bf16x8 ah = __builtin_bit_cast(bf16x8, a_lds[buf][(wm * 4 + rt) * 64 + lane]);
#pragma unroll
            for (int ct = 0; ct < 4; ++ct)
                acc[rt][ct] = __builtin_amdgcn_mfma_f32_16x16x32_bf16(ah, bh[ct], acc[rt][ct], 0, 0, 0);
        }
        if (nx) awrite(buf ^ 1);
        __syncthreads();
    }

    // epilogue: dist = w2 - 2*dot; per-row TOP-2 over this wave's 64 cols;
    // plain store to slot (gx*4+wn) -- no atomics, deterministic.
    const int col_base = gx * 256 + wn * 64;
    float w2c[4];
#pragma unroll
    for (int ct = 0; ct < 4; ++ct) {
        const int col = col_base + ct * 16 + (lane & 15);
        float s = 0.f;
#pragma unroll
        for (int p = 0; p < 16; ++p) s += w2p[p * K + col];
        w2c[ct] = s;
    }
    const int slot = gx * 4 + wn;

#pragma unroll
    for (int rt = 0; rt < 4; ++rt) {
#pragma unroll
        for (int reg = 0; reg < 4; ++reg) {
            u64 k1 = ~0ull, k2 = ~0ull;
#pragma unroll
            for (int ct = 0; ct < 4; ++ct) {
                float dist = w2c[ct] - 2.0f * acc[rt][ct][reg];
                uint su = __float_as_uint(dist);
                su = (su & 0x80000000u) ? ~su : (su | 0x80000000u);
                const u64 key = ((u64)su << 32) | (uint)(col_base + ct * 16 + (lane & 15));
                if (key < k1) { k2 = k1; k1 = key; }
                else if (key < k2) { k2 = key; }
            }
#pragma unroll
            for (int m = 1; m < 16; m <<= 1) {
                u64 o1 = __shfl_xor((unsigned long long)k1, m);
                u64 o2 = __shfl_xor((unsigned long long)k2, m);
                u64 lo = k1 < o1 ? k1 : o1;
                u64 hi = k1 < o1 ? o1 : k1;
                u64 mn2 = k2 < o2 ? k2 : o2;
                k1 = lo;
                k2 = hi < mn2 ? hi : mn2;
            }
            if ((lane & 15) == 0) {
                const int row = gy * 128 + wm * 64 + rt * 16 + (lane >> 4) * 4 + reg;
                keysA[(size_t)slot * BATCH + row] = k1;
                keysB[(size_t)slot * BATCH + row] = k2;
            }
        }
    }
}

// ---- verify: merge 16 slots/row -> global top-2; margin test; hist; list ----
__global__ void k_verify(const u64* __restrict__ keysA, const u64* __restrict__ keysB,
                         int* __restrict__ am, int* __restrict__ counts,
                         u64* __restrict__ list, int* __restrict__ listcnt,
                         float* __restrict__ esum) {
    const int r = blockIdx.x * 256 + threadIdx.x;
    // zero esum (2MB / 65536 threads = 8 floats)
    f32x4 z = {0.f, 0.f, 0.f, 0.f};
    ((f32x4*)esum)[r * 2] = z;
    ((f32x4*)esum)[r * 2 + 1] = z;

    u64 m1 = ~0ull, s = ~0ull;
    int i1 = 0;
#pragma unroll
    for (int i = 0; i < 16; ++i) {
        u64 a = keysA[(size_t)i * BATCH + r];
        if (a < m1) { s = m1; m1 = a; i1 = i; }
        else if (a < s) s = a;
    }
    u64 b = keysB[(size_t)i1 * BATCH + r];
    u64 m2 = s < b ? s : b;

    const float d1 = dec_key((uint)(m1 >> 32));
    const float d2 = dec_key((uint)(m2 >> 32));
    const int c1 = (int)(uint)m1 & 1023;
    const int c2 = (int)(uint)m2 & 1023;

    if (d2 - d1 > MARGIN) {
        am[r] = c1;
        atomicAdd(&counts[c1], 1);
    } else {
        int p = atomicAdd(listcnt, 1);
        list[p] = ((u64)(uint)r << 32) | ((uint)c1 << 10) | (uint)c2;
    }
}

// ---- recheck: exact f32 distance for the 2 candidates of marginal rows ----
__launch_bounds__(256)
__global__ void k_recheck(const float* __restrict__ x, const float* __restrict__ wT,
                          const float* __restrict__ w2p, const u64* __restrict__ list,
                          const int* __restrict__ listcnt, int* __restrict__ am,
                          int* __restrict__ counts) {
    const int gwid = (blockIdx.x * 256 + threadIdx.x) >> 6;   // 1024 waves
    const int lane = threadIdx.x & 63;
    const int n = *listcnt;
    for (int idx = gwid; idx < n; idx += 1024) {
        const u64 e = list[idx];
        const int r = (int)(e >> 32);
        const int c1 = (int)((e >> 10) & 1023);
        const int c2 = (int)(e & 1023);
        const f32x4 x0 = *(const f32x4*)&x[(size_t)r * VEC + lane * 8];
        const f32x4 x1 = *(const f32x4*)&x[(size_t)r * VEC + lane * 8 + 4];
        float d[2];
        const int cc[2] = {c1, c2};
#pragma unroll
        for (int j = 0; j < 2; ++j) {
            const int c = cc[j];
            const f32x4 w0 = *(const f32x4*)&wT[(size_t)c * VEC + lane * 8];
            const f32x4 w1 = *(const f32x4*)&wT[(size_t)c * VEC + lane * 8 + 4];
            float p = x0[0] * w0[0] + x0[1] * w0[1] + x0[2] * w0[2] + x0[3] * w0[3]
                    + x1[0] * w1[0] + x1[1] * w1[1] + x1[2] * w1[2] + x1[3] * w1[3];
#pragma unroll
            for (int m = 1; m < 64; m <<= 1) p += __shfl_xor(p, m);
            float w2 = 0.f;
#pragma unroll
            for (int q = 0; q < 16; ++q) w2 += w2p[q * K + c];
            d[j] = w2 - 2.0f * p;
        }
        const int win = (d[0] < d[1] || (d[0] == d[1] && c1 < c2)) ? c1 : c2;
        if (lane == 0) {
            am[r] = win;
            atomicAdd(&counts[win], 1);
        }
    }
}

// ---- scan of counts -> offsets; EMA cluster sizes -> cs (wave-shuffle) ----
__global__ void k_scan(const int* __restrict__ counts,
                       const float* __restrict__ cluster_size,
                       int* __restrict__ offsets, float* __restrict__ cs) {
    __shared__ int wsum[16];
    __shared__ float fw[16];
    const int t = threadIdx.x;           // 0..1023
    const int lane = t & 63, wid = t >> 6;
    const int c = counts[t];

    int s = c;
#pragma unroll
    for (int d = 1; d < 64; d <<= 1) {
        int o = __shfl_up(s, d);
        if (lane >= d) s += o;
    }
    float ncs = GAMMA * cluster_size[t] + (1.0f - GAMMA) * ((c == 0) ? 1.0f : (float)c);
    float fs = ncs;
#pragma unroll
    for (int d = 32; d > 0; d >>= 1) fs += __shfl_xor(fs, d);

    if (lane == 63) wsum[wid] = s;
    if (lane == 0) fw[wid] = fs;
    __syncthreads();
    if (wid == 0 && lane < 16) {
        int v = wsum[lane];
#pragma unroll
        for (int d = 1; d < 16; d <<= 1) {
            int o = __shfl_up(v, d);
            if (lane >= d) v += o;
        }
        wsum[lane] = v;
    }
    __syncthreads();
    const int base = wid ? wsum[wid - 1] : 0;
    offsets[t] = base + s - c;

    float n = 0.f;
#pragma unroll
    for (int i = 0; i < 16; ++i) n += fw[i];
    cs[t] = (ncs + EPS) / (n + (float)K * EPS) * n;
}

// ---- counting-sort scatter ----
__global__ void k_scatter(const int* __restrict__ am, const int* __restrict__ offsets,
                          int* __restrict__ cursor, int* __restrict__ sorted,
                          int* __restrict__ sortedk) {
    const int b = blockIdx.x * blockDim.x + threadIdx.x;
    const int k = am[b];
    const int pos = atomicAdd(&cursor[k], 1);
    sorted[offsets[k] + pos] = b;
    sortedk[offsets[k] + pos] = k;
}

// ---- balanced segmented reduction: 64 sorted rows per block ----
__launch_bounds__(512)
__global__ void k_segred(const float* __restrict__ x, const int* __restrict__ sorted,
                         const int* __restrict__ sortedk, float* __restrict__ esum) {
    __shared__ int srow[SEG];
    __shared__ int skid[SEG];
    const int b = blockIdx.x;
    const int t = threadIdx.x;
    if (t < SEG) {
        srow[t] = sorted[b * SEG + t];
        skid[t] = sortedk[b * SEG + t];
    }
    __syncthreads();

    float a = 0.f;
    int cur = skid[0];
#pragma unroll 8
    for (int i = 0; i < SEG; ++i) {
        const int k = skid[i];
        if (k != cur) {
            atomicAdd(&esum[(size_t)cur * VEC + t], a);
            a = 0.f;
            cur = k;
        }
        a += x[(size_t)srow[i] * VEC + t];
    }
    atomicAdd(&esum[(size_t)cur * VEC + t], a);
}

// ---- finalize: transpose esum (K,VEC)->(VEC,K), EMA + normalize ----
__launch_bounds__(256)
__global__ void k_finalize(const float* __restrict__ esum, const float* __restrict__ embed_avg,
                           const float* __restrict__ cs, float* __restrict__ out) {
    __shared__ float tile[64][65];
    const int k0 = blockIdx.x * 64;
    const int v0 = blockIdx.y * 64;
    const int c = threadIdx.x & 63;
    const int r0 = threadIdx.x >> 6;
#pragma unroll
    for (int j = 0; j < 16; ++j) {
        const int r = r0 + j * 4;
        tile[r][c] = esum[(size_t)(k0 + r) * VEC + v0 + c];
    }
    __syncthreads();
    const float csk = cs[k0 + c];
#pragma unroll
    for (int j = 0; j < 16; ++j) {
        const int r = r0 + j * 4;
        const size_t o = (size_t)(v0 + r) * K + k0 + c;
        out[o] = (GAMMA * embed_avg[o] + (1.0f - GAMMA) * tile[c][r]) / csk;
    }
}

extern "C" void kernel_launch(void* const* d_in, const int* in_sizes, int n_in,
                              void* d_out, int out_size, void* d_ws, size_t ws_size,
                              hipStream_t stream) {
    const float* x            = (const float*)d_in[0];   // (BATCH, VEC)
    const float* w            = (const float*)d_in[1];   // (VEC, K)
    const float* cluster_size = (const float*)d_in[2];   // (K,)
    const float* embed_avg    = (const float*)d_in[3];   // (VEC, K)
    float* out = (float*)d_out;                          // (VEC, K)

    // ws layout (~23 MB)
    u64*   keysA   = (u64*)d_ws;                          // 16 x BATCH
    u64*   keysB   = keysA + (size_t)16 * BATCH;          // 16 x BATCH
    int*   am      = (int*)(keysB + (size_t)16 * BATCH);  // BATCH
    u64*   list    = (u64*)(am + BATCH);                  // BATCH
    float* w2p     = (float*)(list + BATCH);              // 16 x K
    float* cs      = w2p + 16 * K;                        // K
    int*   cc      = (int*)(cs + K);                      // counts K | cursor K | listcnt 1 (+pad 63)
    int*   counts  = cc;
    int*   cursor  = cc + K;
    int*   listcnt = cc + 2 * K;
    int*   offsets = cc + 2 * K + 64;                     // K
    int*   sorted  = offsets + K;                         // BATCH
    int*   sortedk = sorted + BATCH;                      // BATCH
    float* esum    = (float*)(sortedk + BATCH);           // (K, VEC), 2 MB
    us8*   wpk     = (us8*)(esum + (size_t)K * VEC);      // 1 MB
    float* wT      = (float*)(wpk + (size_t)64 * 1024);   // (K, VEC), 2 MB

    k_pack_w<<<64, 256, 0, stream>>>(w, wpk, wT, w2p, cc);
    k_gemm<<<2048, 512, 0, stream>>>(x, wpk, w2p, keysA, keysB);
    k_verify<<<BATCH / 256, 256, 0, stream>>>(keysA, keysB, am, counts, list, listcnt, esum);
    k_recheck<<<256, 256, 0, stream>>>(x, wT, w2p, list, listcnt, am, counts);
    k_scan<<<1, K, 0, stream>>>(counts, cluster_size, offsets, cs);
    k_scatter<<<BATCH / 256, 256, 0, stream>>>(am, offsets, cursor, sorted, sortedk);
    k_segred<<<BATCH / SEG, 512, 0, stream>>>(x, sorted, sortedk, esum);
    k_finalize<<<dim3(K / 64, VEC / 64), 256, 0, stream>>>(esum, embed_avg, cs, out);
}